// Round 2
// baseline (389.649 us; speedup 1.0000x reference)
//
#include <hip/hip_runtime.h>

// EGAttention: B=4,H=128,W=128,C=256,NH=8,HD=32. 512 windows x 8 heads.
// Two-pass per (w,n) block: pass1 = QK^T chunks -> row sum-sq + |attn| sum only
// (no S tile in registers); pass2 = recompute QK^T chunk, bias+cos -> P chunk in
// per-wave LDS (no barrier), PV MFMA. Gate + finalize as separate small kernels.

typedef __attribute__((ext_vector_type(8))) short bf16x8;
typedef __attribute__((ext_vector_type(4))) float f32x4;

#define PI_F 3.14159265358979323846f

__device__ __forceinline__ short f2bf(float f) {
    union { float f; unsigned u; } v; v.f = f;
    unsigned r = v.u + 0x7fffu + ((v.u >> 16) & 1u);   // RNE bf16 (inputs finite)
    return (short)(r >> 16);
}

__device__ __forceinline__ bf16x8 load_frag8(const float* __restrict__ p) {
    float4 x0 = *(const float4*)p;
    float4 x1 = *(const float4*)(p + 4);
    bf16x8 r;
    r[0] = f2bf(x0.x); r[1] = f2bf(x0.y); r[2] = f2bf(x0.z); r[3] = f2bf(x0.w);
    r[4] = f2bf(x1.x); r[5] = f2bf(x1.y); r[6] = f2bf(x1.z); r[7] = f2bf(x1.w);
    return r;
}

__global__ __launch_bounds__(256, 4) void eg_attn_main(
    const float* __restrict__ q, const float* __restrict__ k,
    const float* __restrict__ v, float* __restrict__ xu,
    float* __restrict__ part)
{
    const int bx = blockIdx.x;
    const int w = bx >> 3;          // window (0..511)
    const int n = bx & 7;           // head
    const int t = threadIdx.x;
    const int lane = t & 63, wv = t >> 6;
    const int quad = lane >> 4, l15 = lane & 15;
    const int m0 = wv * 32;

    __shared__ float gd[256];                        // bias(j-i) = 2*sin(d*pi/127)
    __shared__ __align__(16) short vt[32 * 136];     // V^T bf16 [d][j]
    __shared__ __align__(16) short pw[4][32 * 40];   // per-wave P chunk [32 rows][32+8 cols]
    __shared__ float redsum[4];

    const float* qb = q + (size_t)(w * 128) * 256 + n * 32;
    const float* kb = k + (size_t)(w * 128) * 256 + n * 32;

    // Q fragments (kept in regs for both passes)
    bf16x8 aq[2];
    aq[0] = load_frag8(qb + (m0 + l15) * 256 + quad * 8);
    aq[1] = load_frag8(qb + (m0 + 16 + l15) * 256 + quad * 8);

    if (t < 255) gd[t] = 2.0f * __sinf((float)(t - 127) * (PI_F / 127.0f));

    // stage V^T (bf16) into LDS: thread t -> row j=t&127, d-range (t>>7)*16..+15
    {
        const int j = t & 127, dq = t >> 7;
        const float* vp = v + (size_t)(w * 128 + j) * 256 + n * 32 + dq * 16;
        float4 a0 = ((const float4*)vp)[0];
        float4 a1 = ((const float4*)vp)[1];
        float4 a2 = ((const float4*)vp)[2];
        float4 a3 = ((const float4*)vp)[3];
        float tmp[16] = {a0.x, a0.y, a0.z, a0.w, a1.x, a1.y, a1.z, a1.w,
                         a2.x, a2.y, a2.z, a2.w, a3.x, a3.y, a3.z, a3.w};
#pragma unroll
        for (int e = 0; e < 16; e++)
            vt[(dq * 16 + e) * 136 + j] = f2bf(tmp[e]);
    }
    __syncthreads();   // gd + vt ready

    const float cb = 0.1f * __sinf((float)(w & 127) * (PI_F / 128.0f));

    // ---- pass 1: row sum-of-squares + window |attn| sum (S discarded) ----
    float ss[2][4] = {{0.f, 0.f, 0.f, 0.f}, {0.f, 0.f, 0.f, 0.f}};
    float lsum = 0.f;
#pragma unroll
    for (int tj = 0; tj < 8; tj++) {
        bf16x8 bk = load_frag8(kb + (tj * 16 + l15) * 256 + quad * 8);
        const int j = tj * 16 + l15;
#pragma unroll
        for (int ti = 0; ti < 2; ti++) {
            f32x4 z = {0.f, 0.f, 0.f, 0.f};
            f32x4 c = __builtin_amdgcn_mfma_f32_16x16x32_bf16(aq[ti], bk, z, 0, 0, 0);
#pragma unroll
            for (int r = 0; r < 4; r++) {
                const int i = m0 + ti * 16 + quad * 4 + r;
                const float val = c[r] + cb * gd[j - i + 127];
                ss[ti][r] += val * val;
                lsum += fabsf(val);
            }
        }
    }

    // per-row inverse norms (reduce over the 16 lanes of the quad = 16 cols/chunk)
    float rs[2][4];
#pragma unroll
    for (int ti = 0; ti < 2; ti++)
#pragma unroll
        for (int r = 0; r < 4; r++) {
            float s = ss[ti][r];
            s += __shfl_xor(s, 1);
            s += __shfl_xor(s, 2);
            s += __shfl_xor(s, 4);
            s += __shfl_xor(s, 8);
            rs[ti][r] = 1.57079632679f / fmaxf(sqrtf(s), 1e-12f);
        }

    // window |attn| sum -> per-block partial (no atomics, no memset)
#pragma unroll
    for (int mask = 1; mask < 64; mask <<= 1) lsum += __shfl_xor(lsum, mask);
    if (lane == 0) redsum[wv] = lsum;
    __syncthreads();
    if (t == 0) part[bx] = redsum[0] + redsum[1] + redsum[2] + redsum[3];

    // ---- pass 2: recompute S chunk, P = 1-cos, per-wave LDS, PV MFMA ----
    f32x4 xacc[2][2];
#pragma unroll
    for (int ti = 0; ti < 2; ti++)
#pragma unroll
        for (int tn = 0; tn < 2; tn++) {
            f32x4 z = {0.f, 0.f, 0.f, 0.f};
            xacc[ti][tn] = z;
        }

    short* pwm = pw[wv];
#pragma unroll
    for (int kk = 0; kk < 4; kk++) {
#pragma unroll
        for (int tjl = 0; tjl < 2; tjl++) {
            const int tj = kk * 2 + tjl;
            bf16x8 bk = load_frag8(kb + (tj * 16 + l15) * 256 + quad * 8);
            const int j = tj * 16 + l15;
#pragma unroll
            for (int ti = 0; ti < 2; ti++) {
                f32x4 z = {0.f, 0.f, 0.f, 0.f};
                f32x4 c = __builtin_amdgcn_mfma_f32_16x16x32_bf16(aq[ti], bk, z, 0, 0, 0);
#pragma unroll
                for (int r = 0; r < 4; r++) {
                    const int iloc = ti * 16 + quad * 4 + r;
                    const float val = c[r] + cb * gd[j - (m0 + iloc) + 127];
                    const float p = 1.0f - __cosf(val * rs[ti][r]);
                    pwm[iloc * 40 + tjl * 16 + l15] = f2bf(p);
                }
            }
        }
        // intra-wave LDS write->read: DS pipe is in-order per wave; compiler
        // inserts the lgkmcnt wait for the aliasing shared object.
#pragma unroll
        for (int ti = 0; ti < 2; ti++) {
            bf16x8 pa = *(const bf16x8*)&pwm[(ti * 16 + l15) * 40 + quad * 8];
#pragma unroll
            for (int tn = 0; tn < 2; tn++) {
                bf16x8 vf = *(const bf16x8*)&vt[(tn * 16 + l15) * 136 + kk * 32 + quad * 8];
                xacc[ti][tn] = __builtin_amdgcn_mfma_f32_16x16x32_bf16(pa, vf, xacc[ti][tn], 0, 0, 0);
            }
        }
    }

    // store ungated x_u
    float* ob = xu + (size_t)(w * 128) * 256 + n * 32;
#pragma unroll
    for (int ti = 0; ti < 2; ti++)
#pragma unroll
        for (int tn = 0; tn < 2; tn++)
#pragma unroll
            for (int r = 0; r < 4; r++) {
                const int i = m0 + ti * 16 + quad * 4 + r;
                ob[i * 256 + tn * 16 + l15] = xacc[ti][tn][r];
            }
}

// part[4096] (one per (w,n) block) -> window sums -> M_w = max(s/smax, 0.5)
__global__ __launch_bounds__(512) void eg_gate(const float* __restrict__ part,
                                               float* __restrict__ M)
{
    const int t = threadIdx.x;   // 512 threads = 512 windows
    __shared__ float red[8];
    const float4* p4 = (const float4*)(part + t * 8);
    float4 a0 = p4[0], a1 = p4[1];
    const float s = a0.x + a0.y + a0.z + a0.w + a1.x + a1.y + a1.z + a1.w;
    float m = s;
#pragma unroll
    for (int mask = 1; mask < 64; mask <<= 1) m = fmaxf(m, __shfl_xor(m, mask));
    if ((t & 63) == 0) red[t >> 6] = m;
    __syncthreads();
    if (t == 0) {
        float mm = red[0];
#pragma unroll
        for (int i = 1; i < 8; i++) mm = fmaxf(mm, red[i]);
        red[0] = mm;
    }
    __syncthreads();
    M[t] = fmaxf(s / red[0], 0.5f);
}

// out = x_u * M + res * (1 - M)
__global__ __launch_bounds__(256) void eg_finalize(float* __restrict__ out,
                                                   const float* __restrict__ res,
                                                   const float* __restrict__ M)
{
    const int tid = blockIdx.x * 256 + threadIdx.x;   // 4194304 float4s
    const float Mw = M[tid >> 13];                    // window = (tid*4)>>15
    const float om = 1.0f - Mw;
    float4 x = ((const float4*)out)[tid];
    float4 r = ((const float4*)res)[tid];
    x.x = x.x * Mw + r.x * om;
    x.y = x.y * Mw + r.y * om;
    x.z = x.z * Mw + r.z * om;
    x.w = x.w * Mw + r.w * om;
    ((float4*)out)[tid] = x;
}

extern "C" void kernel_launch(void* const* d_in, const int* in_sizes, int n_in,
                              void* d_out, int out_size, void* d_ws, size_t ws_size,
                              hipStream_t stream) {
    const float* qkv = (const float*)d_in[0];
    const float* res = (const float*)d_in[1];
    const long plane = 16777216L;               // B*HW*C
    const float* q = qkv;
    const float* k = qkv + plane;
    const float* v = qkv + 2 * plane;
    float* out = (float*)d_out;

    float* part = (float*)d_ws;                 // 4096 floats (per-block partials)
    float* M = part + 4096;                     // 512 floats

    eg_attn_main<<<4096, 256, 0, stream>>>(q, k, v, out, part);
    eg_gate<<<1, 512, 0, stream>>>(part, M);
    eg_finalize<<<16384, 256, 0, stream>>>(out, res, M);
}